// Round 6
// baseline (50.698 us; speedup 1.0000x reference)
//
#include <hip/hip_runtime.h>
#include <math.h>

#define D 128
#define G 256

// ws layout:
//   [0,      512)           u  (128 f32) = Wp @ We[0:G]
//   [512,    516)           c  (scalar)  = bp . We[0:G]
//   [1024,   1024 + 4*B)    s[B]   per-graph gated sums
//   [65536,  65536 + 4*B)   pg[B]  hv[last_idx[g]] . we2

// DPP-based add of a permuted copy (VALU pipe, no LDS/DS traffic).
template <int CTRL>
__device__ __forceinline__ float dpp_add(float x) {
    int yi = __builtin_amdgcn_update_dpp(0, __float_as_int(x), CTRL, 0xf, 0xf, true);
    return x + __int_as_float(yi);
}

// Sum over each 16-lane row, result in every lane of the row.
// xor1 (quad_perm[1,0,3,2]=0xB1), xor2 (quad_perm[2,3,0,1]=0x4E),
// then rotate-by-4 (0x124) and rotate-by-8 (0x128) within the row.
__device__ __forceinline__ float row16_sum(float x) {
    x = dpp_add<0xB1>(x);
    x = dpp_add<0x4E>(x);
    x = dpp_add<0x124>(x);
    x = dpp_add<0x128>(x);
    return x;
}

// One 64-lane wave per block, role by blockIdx.x:
//   [0,128)          : u[b] = Wp[b,:] . We[0:256]
//   128              : c = bp . We[0:256]
//   [129, 129+nzero) : zero s (float4 stores)
__global__ void prep_kernel(const float* __restrict__ Wp,
                            const float* __restrict__ bp,
                            const float* __restrict__ We,
                            float* __restrict__ u,
                            float* __restrict__ c,
                            float* __restrict__ s,
                            int B) {
    int b    = blockIdx.x;
    int lane = threadIdx.x;   // 0..63

    if (b < 129) {
        const float* row = (b < D) ? (Wp + (size_t)b * G) : bp;
        float4 rv = ((const float4*)row)[lane];
        float4 wv = ((const float4*)We)[lane];
        float p = rv.x * wv.x + rv.y * wv.y + rv.z * wv.z + rv.w * wv.w;
        #pragma unroll
        for (int m = 32; m >= 1; m >>= 1) p += __shfl_xor(p, m, 64);
        if (lane == 0) {
            if (b < D) u[b] = p;
            else       *c  = p;
        }
        return;
    }
    int idx4 = (b - 129) * 64 + lane;            // float4 index into s
    if (idx4 * 4 + 3 < B) ((float4*)s)[idx4] = make_float4(0.f, 0.f, 0.f, 0.f);
    else {
        for (int j = idx4 * 4; j < B; ++j) s[j] = 0.f;   // tail (no-op if B%4==0)
    }
}

// Grid = gblocks + nblocks (256 threads each).
//   blocks [0, gblocks):  gather pg[g] = hv[last_idx[g]] . we2 (8 graphs/block)
//                         — independent of prep outputs; latency hides under
//                         the streaming blocks' BW-bound run.
//   blocks [gblocks, ..): streaming. One 32-lane half-wave per node row.
//                         Each wave owns a contiguous even chunk; seg_ids is
//                         sorted, so the leader lane keeps a running
//                         (segment, acc) and flushes one atomicAdd per
//                         segment change. Reduce = DPP + one shfl_xor(16).
__global__ void node_kernel(const float* __restrict__ hv,
                            const float* __restrict__ Wg,
                            const float* __restrict__ bg,
                            const int*   __restrict__ seg_ids,
                            const float* __restrict__ u,
                            const float* __restrict__ cptr,
                            const float* __restrict__ We,
                            const int*   __restrict__ last_idx,
                            float*       __restrict__ s,
                            float*       __restrict__ pg,
                            int N, int B, int chunk, int gblocks) {
    if ((int)blockIdx.x < gblocks) {
        int g  = blockIdx.x * 8 + (threadIdx.x >> 5);
        int li = threadIdx.x & 31;
        if (g >= B) return;
        int row = last_idx[g];
        float4 v = ((const float4*)hv)[(size_t)row * 32 + li];
        float4 w = ((const float4*)We)[64 + li];   // we2 = We[256:384]
        float p = v.x * w.x + v.y * w.y + v.z * w.z + v.w * w.w;
        p = row16_sum(p);
        p += __shfl_xor(p, 16, 64);
        if (li == 0) pg[g] = p;
        return;
    }

    int tid  = (blockIdx.x - gblocks) * blockDim.x + threadIdx.x;
    int wave = tid >> 6;
    int lane = threadIdx.x & 63;
    int half = lane >> 5;   // which row of the pair
    int li   = lane & 31;   // lane within half

    int start = wave * chunk;
    if (start >= N) return;
    int end = min(start + chunk, N);   // start, end, N all even -> no tail branch

    const float4* hv4 = (const float4*)hv;
    float4 wg4 = ((const float4*)Wg)[li];   // constant per lane, hoisted
    float4 u4  = ((const float4*)u)[li];
    float  bgv = *bg;
    float  cv  = *cptr;

    int   cur = -1;
    float acc = 0.f;

    for (int r0 = start; r0 < end; r0 += 2) {
        int row = r0 + half;
        float4 v = hv4[(size_t)row * 32 + li];
        int   seg = seg_ids[row];            // broadcast load, uniform per half
        float p1 = v.x * wg4.x + v.y * wg4.y + v.z * wg4.z + v.w * wg4.w;
        float p2 = v.x * u4.x  + v.y * u4.y  + v.z * u4.z  + v.w * u4.w;
        p1 = row16_sum(p1);
        p2 = row16_sum(p2);
        p1 += __shfl_xor(p1, 16, 64);        // cross the two 16-rows of the half
        p2 += __shfl_xor(p2, 16, 64);
        float gate = 1.f / (1.f + __expf(-(p1 + bgv)));
        float val = gate * (p2 + cv);
        if (li == 0) {
            if (seg != cur) {
                if (cur >= 0) atomicAdd(&s[cur], acc);
                cur = seg;
                acc = val;
            } else {
                acc += val;
            }
        }
    }
    if (li == 0 && cur >= 0) atomicAdd(&s[cur], acc);
}

// One thread per graph: logit = s[g] + pg[g] + be, stable log-sigmoid + select.
__global__ void final_kernel(const float* __restrict__ s,
                             const float* __restrict__ pg,
                             const float* __restrict__ be,
                             const int*   __restrict__ a,
                             float*       __restrict__ out,
                             int B) {
    int g = blockIdx.x * blockDim.x + threadIdx.x;
    if (g >= B) return;
    float logit = s[g] + pg[g] + *be;
    float x = (a[g] != 0) ? logit : -logit;       // log_probs[:, a]
    // log_sigmoid(x) = min(x,0) - log1p(exp(-|x|))
    out[g] = fminf(x, 0.f) - log1pf(__expf(-fabsf(x)));
}

extern "C" void kernel_launch(void* const* d_in, const int* in_sizes, int n_in,
                              void* d_out, int out_size, void* d_ws, size_t ws_size,
                              hipStream_t stream) {
    const float* hv       = (const float*)d_in[0];
    const float* Wg       = (const float*)d_in[1];
    const float* bg       = (const float*)d_in[2];
    const float* Wp       = (const float*)d_in[3];
    const float* bp       = (const float*)d_in[4];
    const float* We       = (const float*)d_in[5];
    const float* be       = (const float*)d_in[6];
    const int*   seg_ids  = (const int*)d_in[7];
    const int*   last_idx = (const int*)d_in[8];
    const int*   a        = (const int*)d_in[9];
    float*       out      = (float*)d_out;

    int N = in_sizes[0] / D;
    int B = in_sizes[8];

    float* u  = (float*)d_ws;
    float* c  = (float*)((char*)d_ws + 512);
    float* s  = (float*)((char*)d_ws + 1024);
    float* pg = (float*)((char*)d_ws + 65536);

    // prep: 129 weight blocks + zero-s blocks
    int nzero = (B / 4 + 63) / 64;
    prep_kernel<<<129 + nzero, 64, 0, stream>>>(Wp, bp, We, u, c, s, B);

    // node: gather blocks (8 graphs each) + streaming blocks, one dispatch
    const int nblocks = 2048;                 // 8192 streaming waves
    int gblocks = (B + 7) / 8;
    int waves = nblocks * 256 / 64;
    int chunk = (N + waves - 1) / waves;
    chunk = (chunk + 1) & ~1;                 // even so both halves stay in-chunk
    node_kernel<<<gblocks + nblocks, 256, 0, stream>>>(
        hv, Wg, bg, seg_ids, u, c, We, last_idx, s, pg, N, B, chunk, gblocks);

    int fblocks = (B + 255) / 256;
    final_kernel<<<fblocks, 256, 0, stream>>>(s, pg, be, a, out, B);
}

// Round 7
// 50.514 us; speedup vs baseline: 1.0036x; 1.0036x over previous
//
#include <hip/hip_runtime.h>
#include <math.h>

#define D 128
#define G 256

// ws layout:
//   [0,      512)           u  (128 f32) = Wp @ We[0:G]
//   [512,    516)           c  (scalar)  = bp . We[0:G]
//   [1024,   1024 + 4*B)    s[B]   per-graph gated sums
//   [65536,  65536 + 4*B)   pg[B]  hv[last_idx[g]] . we2

// DPP-based add of a permuted copy (VALU pipe, no LDS/DS traffic).
template <int CTRL>
__device__ __forceinline__ float dpp_add(float x) {
    int yi = __builtin_amdgcn_update_dpp(0, __float_as_int(x), CTRL, 0xf, 0xf, true);
    return x + __int_as_float(yi);
}

// Sum over each 16-lane row, result in every lane of the row.
__device__ __forceinline__ float row16_sum(float x) {
    x = dpp_add<0xB1>(x);    // quad_perm xor1
    x = dpp_add<0x4E>(x);    // quad_perm xor2
    x = dpp_add<0x124>(x);   // row rotate 4
    x = dpp_add<0x128>(x);   // row rotate 8
    return x;
}

// One 64-lane wave per block, role by blockIdx.x:
//   [0,128)          : u[b] = Wp[b,:] . We[0:256]
//   128              : c = bp . We[0:256]
//   [129, 129+nzero) : zero s (float4 stores)
__global__ void prep_kernel(const float* __restrict__ Wp,
                            const float* __restrict__ bp,
                            const float* __restrict__ We,
                            float* __restrict__ u,
                            float* __restrict__ c,
                            float* __restrict__ s,
                            int B) {
    int b    = blockIdx.x;
    int lane = threadIdx.x;   // 0..63

    if (b < 129) {
        const float* row = (b < D) ? (Wp + (size_t)b * G) : bp;
        float4 rv = ((const float4*)row)[lane];
        float4 wv = ((const float4*)We)[lane];
        float p = rv.x * wv.x + rv.y * wv.y + rv.z * wv.z + rv.w * wv.w;
        #pragma unroll
        for (int m = 32; m >= 1; m >>= 1) p += __shfl_xor(p, m, 64);
        if (lane == 0) {
            if (b < D) u[b] = p;
            else       *c  = p;
        }
        return;
    }
    int idx4 = (b - 129) * 64 + lane;            // float4 index into s
    if (idx4 * 4 + 3 < B) ((float4*)s)[idx4] = make_float4(0.f, 0.f, 0.f, 0.f);
    else {
        for (int j = idx4 * 4; j < B; ++j) s[j] = 0.f;   // tail (no-op if B%4==0)
    }
}

// Exactly nblocks streaming blocks (8192 waves = one full residency round).
// Each 32-lane half-wave processes one node row per iteration (128 f32 =
// 32 x float4). seg_ids is sorted, so the leader lane keeps a running
// (segment, acc) and flushes one atomicAdd per segment change.
// AFTER its streaming chunk, each half-wave does one gather
// pg[g] = hv[last_idx[g]] . we2 — overlaps the stream-finish tail, no
// registers live across the loop.
__global__ __launch_bounds__(256, 8)
void node_kernel(const float* __restrict__ hv,
                 const float* __restrict__ Wg,
                 const float* __restrict__ bg,
                 const int*   __restrict__ seg_ids,
                 const float* __restrict__ u,
                 const float* __restrict__ cptr,
                 const float* __restrict__ We,
                 const int*   __restrict__ last_idx,
                 float*       __restrict__ s,
                 float*       __restrict__ pg,
                 int N, int B, int chunk, int nwaves) {
    int tid  = blockIdx.x * blockDim.x + threadIdx.x;
    int wave = tid >> 6;
    int lane = threadIdx.x & 63;
    int half = lane >> 5;   // which row of the pair
    int li   = lane & 31;   // lane within half

    const float4* hv4 = (const float4*)hv;

    int start = wave * chunk;
    if (start < N) {
        int end = min(start + chunk, N);   // start, end, N all even

        float4 wg4 = ((const float4*)Wg)[li];   // constant per lane, hoisted
        float4 u4  = ((const float4*)u)[li];
        float  bgv = *bg;
        float  cv  = *cptr;

        int   cur = -1;
        float acc = 0.f;

        for (int r0 = start; r0 < end; r0 += 2) {
            int row = r0 + half;
            float4 v = hv4[(size_t)row * 32 + li];
            int   seg = seg_ids[row];        // broadcast load, uniform per half
            float p1 = v.x * wg4.x + v.y * wg4.y + v.z * wg4.z + v.w * wg4.w;
            float p2 = v.x * u4.x  + v.y * u4.y  + v.z * u4.z  + v.w * u4.w;
            p1 = row16_sum(p1);
            p2 = row16_sum(p2);
            p1 += __shfl_xor(p1, 16, 64);    // cross the two 16-rows of the half
            p2 += __shfl_xor(p2, 16, 64);
            float gate = 1.f / (1.f + __expf(-(p1 + bgv)));
            float val = gate * (p2 + cv);
            if (li == 0) {
                if (seg != cur) {
                    if (cur >= 0) atomicAdd(&s[cur], acc);
                    cur = seg;
                    acc = val;
                } else {
                    acc += val;
                }
            }
        }
        if (li == 0 && cur >= 0) atomicAdd(&s[cur], acc);
    }

    // gather tail: one graph per half-wave
    float4 w24 = ((const float4*)We)[64 + li];   // we2 = We[256:384]
    int nhw = nwaves * 2;
    for (int g = wave * 2 + half; g < B; g += nhw) {
        int row = last_idx[g];
        float4 v = hv4[(size_t)row * 32 + li];
        float p = v.x * w24.x + v.y * w24.y + v.z * w24.z + v.w * w24.w;
        p = row16_sum(p);
        p += __shfl_xor(p, 16, 64);
        if (li == 0) pg[g] = p;
    }
}

// One thread per graph: logit = s[g] + pg[g] + be, stable log-sigmoid + select.
__global__ void final_kernel(const float* __restrict__ s,
                             const float* __restrict__ pg,
                             const float* __restrict__ be,
                             const int*   __restrict__ a,
                             float*       __restrict__ out,
                             int B) {
    int g = blockIdx.x * blockDim.x + threadIdx.x;
    if (g >= B) return;
    float logit = s[g] + pg[g] + *be;
    float x = (a[g] != 0) ? logit : -logit;       // log_probs[:, a]
    // log_sigmoid(x) = min(x,0) - log1p(exp(-|x|))
    out[g] = fminf(x, 0.f) - log1pf(__expf(-fabsf(x)));
}

extern "C" void kernel_launch(void* const* d_in, const int* in_sizes, int n_in,
                              void* d_out, int out_size, void* d_ws, size_t ws_size,
                              hipStream_t stream) {
    const float* hv       = (const float*)d_in[0];
    const float* Wg       = (const float*)d_in[1];
    const float* bg       = (const float*)d_in[2];
    const float* Wp       = (const float*)d_in[3];
    const float* bp       = (const float*)d_in[4];
    const float* We       = (const float*)d_in[5];
    const float* be       = (const float*)d_in[6];
    const int*   seg_ids  = (const int*)d_in[7];
    const int*   last_idx = (const int*)d_in[8];
    const int*   a        = (const int*)d_in[9];
    float*       out      = (float*)d_out;

    int N = in_sizes[0] / D;
    int B = in_sizes[8];

    float* u  = (float*)d_ws;
    float* c  = (float*)((char*)d_ws + 512);
    float* s  = (float*)((char*)d_ws + 1024);
    float* pg = (float*)((char*)d_ws + 65536);

    // prep: 129 weight blocks + zero-s blocks
    int nzero = (B / 4 + 63) / 64;
    prep_kernel<<<129 + nzero, 64, 0, stream>>>(Wp, bp, We, u, c, s, B);

    // node: exactly one residency round (8 blocks/CU x 256 CU), gather folded
    const int nblocks = 2048;
    int nwaves = nblocks * 256 / 64;          // 8192
    int chunk = (N + nwaves - 1) / nwaves;
    chunk = (chunk + 1) & ~1;                 // even so both halves stay in-chunk
    node_kernel<<<nblocks, 256, 0, stream>>>(
        hv, Wg, bg, seg_ids, u, c, We, last_idx, s, pg, N, B, chunk, nwaves);

    int fblocks = (B + 255) / 256;
    final_kernel<<<fblocks, 256, 0, stream>>>(s, pg, be, a, out, B);
}